// Round 4
// baseline (219.694 us; speedup 1.0000x reference)
//
#include <hip/hip_runtime.h>
#include <stdint.h>
#include <stddef.h>

// ---------------------------------------------------------------------------
// AttentionLayer: x[4,2048,1024] f32, W_qkv[3072,1024], b_qkv[3072],
//                 W_proj[1024,1024], b_proj[1024]  -> out[4,2048,1024] f32
// bf16 MFMA GEMMs in NT form. g128: 128x128 tile, BK=32, 4 waves, 32KB LDS
// double-buffer -> 4 blocks/CU; 2-phase loop (1 barrier/tile) so cross-block
// TLP hides stage/drain latency. T1 XCD swizzle + T2 read-swizzle retained.
// ---------------------------------------------------------------------------

typedef __attribute__((ext_vector_type(8))) short bf16x8;
typedef __attribute__((ext_vector_type(4))) float f32x4;

__device__ __forceinline__ unsigned short f2bf(float f) {
  unsigned u = __float_as_uint(f);
  u += 0x7fffu + ((u >> 16) & 1u);
  return (unsigned short)(u >> 16);
}
__device__ __forceinline__ float bf2f(unsigned short h) {
  return __uint_as_float(((unsigned)h) << 16);
}

typedef const __attribute__((address_space(1))) void* gas_ptr;
typedef __attribute__((address_space(3))) void* las_ptr;

__device__ __forceinline__ void gload_lds16(const void* g, void* l) {
  __builtin_amdgcn_global_load_lds((gas_ptr)(uintptr_t)g,
                                   (las_ptr)(uint32_t)(uintptr_t)l, 16, 0, 0);
}

__device__ __forceinline__ f32x4 mfma16(bf16x8 a, bf16x8 b, f32x4 c) {
  return __builtin_amdgcn_mfma_f32_16x16x32_bf16(a, b, c, 0, 0, 0);
}

// --------------------------- fp32 -> bf16 cast -----------------------------
__global__ __launch_bounds__(256) void cvt_f32_bf16(
    const float* __restrict__ in, unsigned short* __restrict__ out, int n) {
  int i = (blockIdx.x * blockDim.x + threadIdx.x) * 4;
  int stride = gridDim.x * blockDim.x * 4;
  for (; i < n; i += stride) {
    float4 v = *reinterpret_cast<const float4*>(in + i);
    ushort4 o;
    o.x = f2bf(v.x); o.y = f2bf(v.y); o.z = f2bf(v.z); o.w = f2bf(v.w);
    *reinterpret_cast<ushort4*>(out + i) = o;
  }
}

// =============================== g128 ======================================
// Tile 128x128, BK=32, 256 threads (4 waves as 2x2, each wave 64x64 out).
// LDS tile [128][32] bf16, row = 64B. Swizzle: 16B colGroup ^= (row>>1)&3
// -> ds_read_b128 at bank-BW floor (2-way only). Stage pre-swizzles the
// GLOBAL source column; LDS dest stays linear (global_load_lds constraint).

__device__ __forceinline__ void stage128(const unsigned short* __restrict__ P,
                                         int ld, unsigned short* dst, int tid) {
  const int w = tid >> 6, l = tid & 63;
  const int rr = l >> 2;                                   // row within 64-row chunk (w*16 + ...)
  const int cswz = (((l & 3) ^ ((l >> 3) & 3)) * 8);       // = (l&3) ^ ((row>>1)&3), row bits from l>>2
#pragma unroll
  for (int c = 0; c < 2; ++c) {
    int r = c * 64 + w * 16 + rr;
    gload_lds16(P + (size_t)r * ld + cswz, dst + c * 2048 + w * 512);
  }
}

template <bool OUT_BF16, bool HAS_BIAS>
__global__ __launch_bounds__(256, 4) void g128(
    const unsigned short* __restrict__ A, const unsigned short* __restrict__ B,
    void* __restrict__ Cv, const float* __restrict__ bias,
    int K, int lda, int ldb, int ldc,
    long long strideA, long long strideB, long long strideC, float alpha) {
  __shared__ unsigned short sA[2][128 * 32];
  __shared__ unsigned short sB[2][128 * 32];

  const int bz = blockIdx.z;
  const int gx = gridDim.x;
  int lin = blockIdx.y * gx + blockIdx.x;
  {  // XCD swizzle (all grids used are multiples of 8)
    const int q = (gx * gridDim.y) >> 3;
    lin = (lin & 7) * q + (lin >> 3);
  }
  const int bx = lin % gx, by = lin / gx;
  const int rowBase = by * 128;
  const int colBase = bx * 128;

  const unsigned short* Ap = A + (size_t)bz * (size_t)strideA + (size_t)rowBase * lda;
  const unsigned short* Bp = B + (size_t)bz * (size_t)strideB + (size_t)colBase * ldb;

  const int tid = threadIdx.x;
  const int wid = tid >> 6;
  const int lane = tid & 63;
  const int wr = wid >> 1;          // 0..1
  const int wc = wid & 1;           // 0..1
  const int fr = lane & 15;
  const int kgi = lane >> 4;        // 0..3 k-group
  const int rcol = ((kgi ^ ((fr >> 1) & 3)) * 8);  // swizzled read col (elems)

  const int nt = K >> 5;            // K-tiles of 32

  f32x4 acc[4][4] = {};

  // prologue: stage tile 0
  stage128(Ap, lda, sA[0], tid);
  stage128(Bp, ldb, sB[0], tid);
  asm volatile("s_waitcnt vmcnt(0)" ::: "memory");
  __builtin_amdgcn_sched_barrier(0);
  __builtin_amdgcn_s_barrier();

  for (int t = 0; t < nt; ++t) {
    const int cur = t & 1;
    // issue next-tile staging first (overlaps with reads+MFMA below)
    if (t + 1 < nt) {
      stage128(Ap + (size_t)(t + 1) * 32, lda, sA[cur ^ 1], tid);
      stage128(Bp + (size_t)(t + 1) * 32, ldb, sB[cur ^ 1], tid);
    }
    const unsigned short* sAc = sA[cur];
    const unsigned short* sBc = sB[cur];
    bf16x8 af[4], bv[4];
#pragma unroll
    for (int m = 0; m < 4; ++m)
      af[m] = *(const bf16x8*)&sAc[(wr * 64 + m * 16 + fr) * 32 + rcol];
#pragma unroll
    for (int n = 0; n < 4; ++n)
      bv[n] = *(const bf16x8*)&sBc[(wc * 64 + n * 16 + fr) * 32 + rcol];
    asm volatile("s_waitcnt lgkmcnt(0)" ::: "memory");
    __builtin_amdgcn_sched_barrier(0);
    __builtin_amdgcn_s_setprio(1);
#pragma unroll
    for (int m = 0; m < 4; ++m)
#pragma unroll
      for (int n = 0; n < 4; ++n)
        acc[m][n] = mfma16(af[m], bv[n], acc[m][n]);
    __builtin_amdgcn_s_setprio(0);
    __builtin_amdgcn_sched_barrier(0);
    asm volatile("s_waitcnt vmcnt(0)" ::: "memory");
    __builtin_amdgcn_sched_barrier(0);
    __builtin_amdgcn_s_barrier();
  }

  // epilogue: C/D layout col=lane&15, row=(lane>>4)*4+j
  unsigned short* Cb = reinterpret_cast<unsigned short*>(Cv) + (size_t)bz * (size_t)strideC;
  float* Cf = reinterpret_cast<float*>(Cv) + (size_t)bz * (size_t)strideC;
  const int rg = (lane >> 4) * 4;
#pragma unroll
  for (int m = 0; m < 4; ++m) {
    int r0 = rowBase + wr * 64 + m * 16 + rg;
#pragma unroll
    for (int n = 0; n < 4; ++n) {
      int cidx = colBase + wc * 64 + n * 16 + fr;
      float bvs = 0.0f;
      if (HAS_BIAS) bvs = bias[cidx];
#pragma unroll
      for (int j = 0; j < 4; ++j) {
        float v = acc[m][n][j] * alpha + bvs;
        if (OUT_BF16)
          Cb[(size_t)(r0 + j) * ldc + cidx] = f2bf(v);
        else
          Cf[(size_t)(r0 + j) * ldc + cidx] = v;
      }
    }
  }
}

// --------------------------- V transpose -----------------------------------
__global__ void transpose_v(const unsigned short* __restrict__ qkv,
                            unsigned short* __restrict__ vt) {
  __shared__ unsigned short tile[32][33];
  const int b = blockIdx.z;
  const int d0 = blockIdx.x * 32;
  const int s0 = blockIdx.y * 32;
  const int tx = threadIdx.x, ty = threadIdx.y;
#pragma unroll
  for (int i = 0; i < 32; i += 8)
    tile[ty + i][tx] =
        qkv[(size_t)(b * 2048 + s0 + ty + i) * 3072 + 2048 + d0 + tx];
  __syncthreads();
#pragma unroll
  for (int i = 0; i < 32; i += 8)
    vt[((size_t)b * 1024 + d0 + ty + i) * 2048 + s0 + tx] = tile[tx][ty + i];
}

// --------------------------- row softmax (in place, bf16) ------------------
__global__ __launch_bounds__(256) void softmax_rows(unsigned short* __restrict__ s) {
  __shared__ float red[8];
  const size_t row = blockIdx.x;
  unsigned short* p = s + row * 2048;
  const int tid = threadIdx.x;

  ushort4 u0 = *reinterpret_cast<const ushort4*>(p + tid * 8);
  ushort4 u1 = *reinterpret_cast<const ushort4*>(p + tid * 8 + 4);
  float v[8];
  v[0] = bf2f(u0.x); v[1] = bf2f(u0.y); v[2] = bf2f(u0.z); v[3] = bf2f(u0.w);
  v[4] = bf2f(u1.x); v[5] = bf2f(u1.y); v[6] = bf2f(u1.z); v[7] = bf2f(u1.w);

  float mx = v[0];
#pragma unroll
  for (int j = 1; j < 8; ++j) mx = fmaxf(mx, v[j]);
#pragma unroll
  for (int off = 32; off; off >>= 1) mx = fmaxf(mx, __shfl_xor(mx, off));
  if ((tid & 63) == 0) red[tid >> 6] = mx;
  __syncthreads();
  mx = fmaxf(fmaxf(red[0], red[1]), fmaxf(red[2], red[3]));

  float e[8], sum = 0.0f;
#pragma unroll
  for (int j = 0; j < 8; ++j) { e[j] = __expf(v[j] - mx); sum += e[j]; }
#pragma unroll
  for (int off = 32; off; off >>= 1) sum += __shfl_xor(sum, off);
  if ((tid & 63) == 0) red[4 + (tid >> 6)] = sum;
  __syncthreads();
  sum = red[4] + red[5] + red[6] + red[7];
  const float inv = 1.0f / sum;

  ushort4 o0, o1;
  o0.x = f2bf(e[0] * inv); o0.y = f2bf(e[1] * inv);
  o0.z = f2bf(e[2] * inv); o0.w = f2bf(e[3] * inv);
  o1.x = f2bf(e[4] * inv); o1.y = f2bf(e[5] * inv);
  o1.z = f2bf(e[6] * inv); o1.w = f2bf(e[7] * inv);
  *reinterpret_cast<ushort4*>(p + tid * 8) = o0;
  *reinterpret_cast<ushort4*>(p + tid * 8 + 4) = o1;
}

// ---------------------------------------------------------------------------
extern "C" void kernel_launch(void* const* d_in, const int* in_sizes, int n_in,
                              void* d_out, int out_size, void* d_ws, size_t ws_size,
                              hipStream_t stream) {
  const float* x     = (const float*)d_in[0];
  const float* Wqkv  = (const float*)d_in[1];
  const float* bqkv  = (const float*)d_in[2];
  const float* Wproj = (const float*)d_in[3];
  const float* bproj = (const float*)d_in[4];
  float* out = (float*)d_out;

  char* ws = (char*)d_ws;
  unsigned short* qkv  = (unsigned short*)(ws + 0);          // 8192x3072 bf16
  unsigned short* xatt = (unsigned short*)(ws + 50331648);   // 8192x1024 bf16
  unsigned short* wq   = (unsigned short*)(ws + 67108864);   // 3072x1024 bf16
  unsigned short* wp   = (unsigned short*)(ws + 73400320);   // 1024x1024 bf16
  unsigned short* vt   = (unsigned short*)(ws + 75497472);   // 4x1024x2048 bf16
  unsigned short* sc   = (unsigned short*)(ws + 92274688);   // 4x2048x2048 bf16

  dim3 blk256(256);

  // 1. casts
  cvt_f32_bf16<<<2048, blk256, 0, stream>>>(x, xatt, 8192 * 1024);
  cvt_f32_bf16<<<1024, blk256, 0, stream>>>(Wqkv, wq, 3072 * 1024);
  cvt_f32_bf16<<<512, blk256, 0, stream>>>(Wproj, wp, 1024 * 1024);

  // 2. QKV projection: [8192,3072] = x @ Wqkv^T + b  (grid 24x64 = 1536)
  g128<true, true><<<dim3(24, 64, 1), blk256, 0, stream>>>(
      xatt, wq, qkv, bqkv, 1024, 1024, 1024, 3072, 0, 0, 0, 1.0f);

  // 3. V transpose -> Vt[b][d][s]
  transpose_v<<<dim3(32, 64, 4), dim3(32, 8), 0, stream>>>(qkv, vt);

  // 4. scores = Q @ K^T / 32  (grid 16x16x4 = 1024)
  g128<true, false><<<dim3(16, 16, 4), blk256, 0, stream>>>(
      qkv, qkv + 1024, sc, nullptr, 1024, 3072, 3072, 2048,
      2048LL * 3072, 2048LL * 3072, 2048LL * 2048, 0.03125f);

  // 5. softmax rows in place
  softmax_rows<<<8192, blk256, 0, stream>>>(sc);

  // 6. attn_out = P @ Vt  (grid 8x16x4 = 512)
  g128<true, false><<<dim3(8, 16, 4), blk256, 0, stream>>>(
      sc, vt, xatt, nullptr, 2048, 2048, 2048, 1024,
      2048LL * 2048, 1024LL * 2048, 2048LL * 1024, 1.0f);

  // 7. out = attn_out @ Wproj^T + b_proj  (grid 8x64 = 512)
  g128<false, true><<<dim3(8, 64, 1), blk256, 0, stream>>>(
      xatt, wp, out, bproj, 1024, 1024, 1024, 1024, 0, 0, 0, 1.0f);
}

// Round 5
// 198.939 us; speedup vs baseline: 1.1043x; 1.1043x over previous
//
#include <hip/hip_runtime.h>
#include <stdint.h>
#include <stddef.h>

// ---------------------------------------------------------------------------
// AttentionLayer: x[4,2048,1024] f32, W_qkv[3072,1024], b_qkv[3072],
//                 W_proj[1024,1024], b_proj[1024]  -> out[4,2048,1024] f32
// bf16 MFMA GEMMs, NT form. QKV split into QK (gemm256, 256 blocks) and
// V (bm128, 256 blocks) so every GEMM dispatch is an exact multiple of 256.
// gemm256: 256x256 8-phase (QK, QK^T). bm128: 128x256 (V, PV, proj).
// ---------------------------------------------------------------------------

typedef __attribute__((ext_vector_type(8))) short bf16x8;
typedef __attribute__((ext_vector_type(4))) float f32x4;

__device__ __forceinline__ unsigned short f2bf(float f) {
  unsigned u = __float_as_uint(f);
  u += 0x7fffu + ((u >> 16) & 1u);
  return (unsigned short)(u >> 16);
}
__device__ __forceinline__ float bf2f(unsigned short h) {
  return __uint_as_float(((unsigned)h) << 16);
}

typedef const __attribute__((address_space(1))) void* gas_ptr;
typedef __attribute__((address_space(3))) void* las_ptr;

__device__ __forceinline__ void gload_lds16(const void* g, void* l) {
  __builtin_amdgcn_global_load_lds((gas_ptr)(uintptr_t)g,
                                   (las_ptr)(uint32_t)(uintptr_t)l, 16, 0, 0);
}

__device__ __forceinline__ f32x4 mfma16(bf16x8 a, bf16x8 b, f32x4 c) {
  return __builtin_amdgcn_mfma_f32_16x16x32_bf16(a, b, c, 0, 0, 0);
}

// --------------------------- fp32 -> bf16 cast -----------------------------
__global__ __launch_bounds__(256) void cvt_f32_bf16(
    const float* __restrict__ in, unsigned short* __restrict__ out, int n) {
  int i = (blockIdx.x * blockDim.x + threadIdx.x) * 4;
  int stride = gridDim.x * blockDim.x * 4;
  for (; i < n; i += stride) {
    float4 v = *reinterpret_cast<const float4*>(in + i);
    ushort4 o;
    o.x = f2bf(v.x); o.y = f2bf(v.y); o.z = f2bf(v.z); o.w = f2bf(v.w);
    *reinterpret_cast<ushort4*>(out + i) = o;
  }
}

// ======================= 256x256 kernel (QK proj, QK^T) ====================
__device__ __forceinline__ void stage_A(const unsigned short* __restrict__ Ap,
                                        int lda, unsigned short* sAb, int h,
                                        int tid) {
  const int wid = tid >> 6, l = tid & 63;
  const int rsub = (l >> 3);
  const int cg = (((l & 7) ^ rsub) * 8);
#pragma unroll
  for (int c = 0; c < 2; ++c) {
    int logical_row = c * 128 + h * 64 + wid * 8 + rsub;
    gload_lds16(Ap + (size_t)logical_row * lda + cg,
                sAb + h * 8192 + c * 4096 + wid * 512);
  }
}

__device__ __forceinline__ void stage_B(const unsigned short* __restrict__ Bp,
                                        int ldb, unsigned short* sBb, int h,
                                        int tid) {
  const int wid = tid >> 6, l = tid & 63;
  const int rsub = (l >> 3);
  const int cg = (((l & 7) ^ rsub) * 8);
  const int ccol = (wid & 3) * 8 + rsub;
#pragma unroll
  for (int c = 0; c < 2; ++c) {
    int wcs = c * 2 + (wid >> 2);
    int logical_col = wcs * 64 + h * 32 + ccol;
    gload_lds16(Bp + (size_t)logical_col * ldb + cg,
                sBb + h * 8192 + c * 4096 + wid * 512);
  }
}

template <bool OUT_BF16, bool HAS_BIAS>
__global__ __launch_bounds__(512, 2) void gemm256(
    const unsigned short* __restrict__ A, const unsigned short* __restrict__ B,
    void* __restrict__ Cv, const float* __restrict__ bias,
    int M, int N, int K, int lda, int ldb, int ldc,
    long long strideA, long long strideB, long long strideC, float alpha) {
  __shared__ unsigned short sA[2][256 * 64];
  __shared__ unsigned short sB[2][256 * 64];

  const int bz = blockIdx.z;
  const int gx = gridDim.x;
  int lin = blockIdx.y * gx + blockIdx.x;
  const int nwg = gx * gridDim.y;
  if ((nwg & 7) == 0) {
    const int q = nwg >> 3;
    lin = (lin & 7) * q + (lin >> 3);
  }
  const int bx = lin % gx, by = lin / gx;
  const int rowBase = by * 256;
  const int colBase = bx * 256;

  const unsigned short* Ap = A + (size_t)bz * (size_t)strideA + (size_t)rowBase * lda;
  const unsigned short* Bp = B + (size_t)bz * (size_t)strideB + (size_t)colBase * ldb;

  const int tid = threadIdx.x;
  const int wid = tid >> 6;
  const int lane = tid & 63;
  const int wr = wid >> 2;
  const int wc = wid & 3;
  const int fr = lane & 15;
  const int kg = (lane >> 4) * 8;
  const int swz = (fr & 7) << 3;
  const int col0 = kg ^ swz;
  const int col1 = (32 + kg) ^ swz;

  const int nt = K >> 6;

  f32x4 acc[8][4] = {};
  bf16x8 af[4][2], bf0[2][2], bf1[2][2];

  stage_A(Ap, lda, sA[0], 0, tid);
  stage_B(Bp, ldb, sB[0], 0, tid);
  stage_B(Bp, ldb, sB[0], 1, tid);
  stage_A(Ap, lda, sA[0], 1, tid);
  if (nt > 1) {
    stage_A(Ap + 64, lda, sA[1], 0, tid);
    stage_B(Bp + 64, ldb, sB[1], 0, tid);
    stage_B(Bp + 64, ldb, sB[1], 1, tid);
    asm volatile("s_waitcnt vmcnt(6)" ::: "memory");
  } else {
    asm volatile("s_waitcnt vmcnt(0)" ::: "memory");
  }
  __builtin_amdgcn_sched_barrier(0);
  __builtin_amdgcn_s_barrier();

  for (int t = 0; t < nt; ++t) {
    const int cur = t & 1;
    const unsigned short* sAc = sA[cur];
    const unsigned short* sBc = sB[cur];

#pragma unroll
    for (int m = 0; m < 4; ++m) {
      int srow = wr * 64 + m * 16 + fr;
      af[m][0] = *(const bf16x8*)&sAc[srow * 64 + col0];
      af[m][1] = *(const bf16x8*)&sAc[srow * 64 + col1];
    }
#pragma unroll
    for (int n = 0; n < 2; ++n) {
      int scol = wc * 32 + n * 16 + fr;
      bf0[n][0] = *(const bf16x8*)&sBc[scol * 64 + col0];
      bf0[n][1] = *(const bf16x8*)&sBc[scol * 64 + col1];
    }
    if (t + 1 < nt) stage_A(Ap + (size_t)(t + 1) * 64, lda, sA[cur ^ 1], 1, tid);
    __builtin_amdgcn_s_barrier();
    asm volatile("s_waitcnt lgkmcnt(0)" ::: "memory");
    __builtin_amdgcn_sched_barrier(0);
    __builtin_amdgcn_s_setprio(1);
#pragma unroll
    for (int m = 0; m < 4; ++m)
#pragma unroll
      for (int n = 0; n < 2; ++n) {
        acc[m][n] = mfma16(af[m][0], bf0[n][0], acc[m][n]);
        acc[m][n] = mfma16(af[m][1], bf0[n][1], acc[m][n]);
      }
    __builtin_amdgcn_s_setprio(0);
    __builtin_amdgcn_sched_barrier(0);
    __builtin_amdgcn_s_barrier();

#pragma unroll
    for (int n = 0; n < 2; ++n) {
      int scol = 128 + wc * 32 + n * 16 + fr;
      bf1[n][0] = *(const bf16x8*)&sBc[scol * 64 + col0];
      bf1[n][1] = *(const bf16x8*)&sBc[scol * 64 + col1];
    }
    if (t + 2 < nt) stage_A(Ap + (size_t)(t + 2) * 64, lda, sA[cur], 0, tid);
    __builtin_amdgcn_s_barrier();
    asm volatile("s_waitcnt lgkmcnt(0)" ::: "memory");
    __builtin_amdgcn_sched_barrier(0);
    __builtin_amdgcn_s_setprio(1);
#pragma unroll
    for (int m = 0; m < 4; ++m)
#pragma unroll
      for (int n = 0; n < 2; ++n) {
        acc[m][2 + n] = mfma16(af[m][0], bf1[n][0], acc[m][2 + n]);
        acc[m][2 + n] = mfma16(af[m][1], bf1[n][1], acc[m][2 + n]);
      }
    __builtin_amdgcn_s_setprio(0);
    __builtin_amdgcn_sched_barrier(0);
    __builtin_amdgcn_s_barrier();

#pragma unroll
    for (int m = 0; m < 4; ++m) {
      int srow = 128 + wr * 64 + m * 16 + fr;
      af[m][0] = *(const bf16x8*)&sAc[srow * 64 + col0];
      af[m][1] = *(const bf16x8*)&sAc[srow * 64 + col1];
    }
    if (t + 2 < nt) stage_B(Bp + (size_t)(t + 2) * 64, ldb, sB[cur], 0, tid);
    __builtin_amdgcn_s_barrier();
    asm volatile("s_waitcnt lgkmcnt(0)" ::: "memory");
    __builtin_amdgcn_sched_barrier(0);
    __builtin_amdgcn_s_setprio(1);
#pragma unroll
    for (int m = 0; m < 4; ++m)
#pragma unroll
      for (int n = 0; n < 2; ++n) {
        acc[4 + m][2 + n] = mfma16(af[m][0], bf1[n][0], acc[4 + m][2 + n]);
        acc[4 + m][2 + n] = mfma16(af[m][1], bf1[n][1], acc[4 + m][2 + n]);
      }
    __builtin_amdgcn_s_setprio(0);
    __builtin_amdgcn_sched_barrier(0);
    __builtin_amdgcn_s_barrier();

    if (t + 2 < nt) stage_B(Bp + (size_t)(t + 2) * 64, ldb, sB[cur], 1, tid);
    __builtin_amdgcn_s_setprio(1);
#pragma unroll
    for (int m = 0; m < 4; ++m)
#pragma unroll
      for (int n = 0; n < 2; ++n) {
        acc[4 + m][n] = mfma16(af[m][0], bf0[n][0], acc[4 + m][n]);
        acc[4 + m][n] = mfma16(af[m][1], bf0[n][1], acc[4 + m][n]);
      }
    __builtin_amdgcn_s_setprio(0);
    __builtin_amdgcn_sched_barrier(0);
    if (t + 2 < nt) {
      asm volatile("s_waitcnt vmcnt(6)" ::: "memory");
    } else if (t + 1 < nt) {
      asm volatile("s_waitcnt vmcnt(0)" ::: "memory");
    }
    __builtin_amdgcn_sched_barrier(0);
    __builtin_amdgcn_s_barrier();
  }

  unsigned short* Cb = reinterpret_cast<unsigned short*>(Cv) + (size_t)bz * (size_t)strideC;
  float* Cf = reinterpret_cast<float*>(Cv) + (size_t)bz * (size_t)strideC;
  const int rg = (lane >> 4) * 4;
#pragma unroll
  for (int m = 0; m < 8; ++m) {
    int r0 = rowBase + wr * 128 + m * 16 + rg;
#pragma unroll
    for (int n = 0; n < 4; ++n) {
      int cidx = colBase + wc * 64 + n * 16 + fr;
      float bv = 0.0f;
      if (HAS_BIAS) bv = bias[cidx];
#pragma unroll
      for (int j = 0; j < 4; ++j) {
        float v = acc[m][n][j] * alpha + bv;
        if (OUT_BF16)
          Cb[(size_t)(r0 + j) * ldc + cidx] = f2bf(v);
        else
          Cf[(size_t)(r0 + j) * ldc + cidx] = v;
      }
    }
  }
}

// ======================= 128x256 kernel (V, PV, proj) ======================
__device__ __forceinline__ void stage_A128(const unsigned short* __restrict__ Ap,
                                           int lda, unsigned short* sAb, int h,
                                           int tid) {
  const int wid = tid >> 6, l = tid & 63;
  const int rsub = (l >> 3);
  const int cg = (((l & 7) ^ rsub) * 8);
  int logical_row = (wid >> 2) * 64 + h * 32 + (wid & 3) * 8 + rsub;
  gload_lds16(Ap + (size_t)logical_row * lda + cg, sAb + h * 4096 + wid * 512);
}

__device__ __forceinline__ void stage_B128(const unsigned short* __restrict__ Bp,
                                           int ldb, unsigned short* sBb, int nh,
                                           int tid) {
  const int wid = tid >> 6, l = tid & 63;
  const int rsub = (l >> 3);
  const int cg = (((l & 7) ^ rsub) * 8);
#pragma unroll
  for (int u = 0; u < 2; ++u) {
    int logical_col = (u * 2 + (wid >> 2)) * 64 + nh * 32 + (wid & 3) * 8 + rsub;
    gload_lds16(Bp + (size_t)logical_col * ldb + cg,
                sBb + nh * 8192 + u * 4096 + wid * 512);
  }
}

template <bool OUT_BF16, bool HAS_BIAS>
__global__ __launch_bounds__(512, 2) void gemm_bm128(
    const unsigned short* __restrict__ A, const unsigned short* __restrict__ B,
    void* __restrict__ Cv, const float* __restrict__ bias,
    int M, int N, int K, int lda, int ldb, int ldc,
    long long strideA, long long strideB, long long strideC, float alpha) {
  __shared__ unsigned short sA[2][128 * 64];
  __shared__ unsigned short sB[2][256 * 64];

  const int bz = blockIdx.z;
  const int gx = gridDim.x;
  int lin = blockIdx.y * gx + blockIdx.x;
  const int nwg = gx * gridDim.y;
  if ((nwg & 7) == 0) {
    const int q = nwg >> 3;
    lin = (lin & 7) * q + (lin >> 3);
  }
  const int bx = lin % gx, by = lin / gx;
  const int rowBase = by * 128;
  const int colBase = bx * 256;

  const unsigned short* Ap = A + (size_t)bz * (size_t)strideA + (size_t)rowBase * lda;
  const unsigned short* Bp = B + (size_t)bz * (size_t)strideB + (size_t)colBase * ldb;

  const int tid = threadIdx.x;
  const int wid = tid >> 6;
  const int lane = tid & 63;
  const int wr = wid >> 2;
  const int wc = wid & 3;
  const int fr = lane & 15;
  const int kg = (lane >> 4) * 8;
  const int swz = (fr & 7) << 3;
  const int col0 = kg ^ swz;
  const int col1 = (32 + kg) ^ swz;

  const int nt = K >> 6;

  f32x4 acc[4][4] = {};
  bf16x8 af[4][2], bfr[4][2];

  stage_A128(Ap, lda, sA[0], 0, tid);
  stage_A128(Ap, lda, sA[0], 1, tid);
  stage_B128(Bp, ldb, sB[0], 0, tid);
  stage_B128(Bp, ldb, sB[0], 1, tid);
  if (nt > 1) {
    stage_A128(Ap + 64, lda, sA[1], 0, tid);
    stage_A128(Ap + 64, lda, sA[1], 1, tid);
    stage_B128(Bp + 64, ldb, sB[1], 0, tid);
    stage_B128(Bp + 64, ldb, sB[1], 1, tid);
    asm volatile("s_waitcnt vmcnt(6)" ::: "memory");
  } else {
    asm volatile("s_waitcnt vmcnt(0)" ::: "memory");
  }
  __builtin_amdgcn_sched_barrier(0);
  __builtin_amdgcn_s_barrier();

  for (int t = 0; t < nt; ++t) {
    const int cur = t & 1;
    const unsigned short* sAc = sA[cur];
    const unsigned short* sBc = sB[cur];

#pragma unroll
    for (int m = 0; m < 2; ++m) {
      int srow = wr * 32 + m * 16 + fr;
      af[m][0] = *(const bf16x8*)&sAc[srow * 64 + col0];
      af[m][1] = *(const bf16x8*)&sAc[srow * 64 + col1];
    }
#pragma unroll
    for (int n = 0; n < 2; ++n) {
      int srow = wc * 32 + n * 16 + fr;
      bfr[n][0] = *(const bf16x8*)&sBc[srow * 64 + col0];
      bfr[n][1] = *(const bf16x8*)&sBc[srow * 64 + col1];
    }
    __builtin_amdgcn_s_barrier();
    asm volatile("s_waitcnt lgkmcnt(0)" ::: "memory");
    __builtin_amdgcn_sched_barrier(0);
    __builtin_amdgcn_s_setprio(1);
#pragma unroll
    for (int m = 0; m < 2; ++m)
#pragma unroll
      for (int n = 0; n < 2; ++n) {
        acc[m][n] = mfma16(af[m][0], bfr[n][0], acc[m][n]);
        acc[m][n] = mfma16(af[m][1], bfr[n][1], acc[m][n]);
      }
    __builtin_amdgcn_s_setprio(0);
    __builtin_amdgcn_sched_barrier(0);
    __builtin_amdgcn_s_barrier();

#pragma unroll
    for (int m = 0; m < 2; ++m) {
      int srow = 64 + wr * 32 + m * 16 + fr;
      af[2 + m][0] = *(const bf16x8*)&sAc[srow * 64 + col0];
      af[2 + m][1] = *(const bf16x8*)&sAc[srow * 64 + col1];
    }
    if (t + 2 < nt) stage_A128(Ap + (size_t)(t + 2) * 64, lda, sA[cur], 0, tid);
    __builtin_amdgcn_s_barrier();
    asm volatile("s_waitcnt lgkmcnt(0)" ::: "memory");
    __builtin_amdgcn_sched_barrier(0);
    __builtin_amdgcn_s_setprio(1);
#pragma unroll
    for (int m = 0; m < 2; ++m)
#pragma unroll
      for (int n = 0; n < 2; ++n) {
        acc[2 + m][n] = mfma16(af[2 + m][0], bfr[n][0], acc[2 + m][n]);
        acc[2 + m][n] = mfma16(af[2 + m][1], bfr[n][1], acc[2 + m][n]);
      }
    __builtin_amdgcn_s_setprio(0);
    __builtin_amdgcn_sched_barrier(0);
    __builtin_amdgcn_s_barrier();

#pragma unroll
    for (int n = 0; n < 2; ++n) {
      int srow = 128 + wc * 32 + n * 16 + fr;
      bfr[2 + n][0] = *(const bf16x8*)&sBc[srow * 64 + col0];
      bfr[2 + n][1] = *(const bf16x8*)&sBc[srow * 64 + col1];
    }
    if (t + 2 < nt) stage_B128(Bp + (size_t)(t + 2) * 64, ldb, sB[cur], 0, tid);
    __builtin_amdgcn_s_barrier();
    asm volatile("s_waitcnt lgkmcnt(0)" ::: "memory");
    __builtin_amdgcn_sched_barrier(0);
    __builtin_amdgcn_s_setprio(1);
#pragma unroll
    for (int m = 0; m < 2; ++m)
#pragma unroll
      for (int n = 0; n < 2; ++n) {
        acc[2 + m][2 + n] = mfma16(af[2 + m][0], bfr[2 + n][0], acc[2 + m][2 + n]);
        acc[2 + m][2 + n] = mfma16(af[2 + m][1], bfr[2 + n][1], acc[2 + m][2 + n]);
      }
    __builtin_amdgcn_s_setprio(0);
    __builtin_amdgcn_sched_barrier(0);
    __builtin_amdgcn_s_barrier();

    if (t + 2 < nt) {
      stage_A128(Ap + (size_t)(t + 2) * 64, lda, sA[cur], 1, tid);
      stage_B128(Bp + (size_t)(t + 2) * 64, ldb, sB[cur], 1, tid);
    }
    __builtin_amdgcn_s_setprio(1);
#pragma unroll
    for (int m = 0; m < 2; ++m)
#pragma unroll
      for (int n = 0; n < 2; ++n) {
        acc[m][2 + n] = mfma16(af[m][0], bfr[2 + n][0], acc[m][2 + n]);
        acc[m][2 + n] = mfma16(af[m][1], bfr[2 + n][1], acc[m][2 + n]);
      }
    __builtin_amdgcn_s_setprio(0);
    __builtin_amdgcn_sched_barrier(0);
    if (t + 2 < nt) {
      asm volatile("s_waitcnt vmcnt(6)" ::: "memory");
    } else if (t + 1 < nt) {
      asm volatile("s_waitcnt vmcnt(0)" ::: "memory");
    }
    __builtin_amdgcn_sched_barrier(0);
    __builtin_amdgcn_s_barrier();
  }

  unsigned short* Cb = reinterpret_cast<unsigned short*>(Cv) + (size_t)bz * (size_t)strideC;
  float* Cf = reinterpret_cast<float*>(Cv) + (size_t)bz * (size_t)strideC;
  const int rg = (lane >> 4) * 4;
#pragma unroll
  for (int m = 0; m < 4; ++m) {
    int r0 = rowBase + wr * 64 + m * 16 + rg;
#pragma unroll
    for (int n = 0; n < 4; ++n) {
      int cidx = colBase + wc * 64 + n * 16 + fr;
      float bv = 0.0f;
      if (HAS_BIAS) bv = bias[cidx];
#pragma unroll
      for (int j = 0; j < 4; ++j) {
        float v = acc[m][n][j] * alpha + bv;
        if (OUT_BF16)
          Cb[(size_t)(r0 + j) * ldc + cidx] = f2bf(v);
        else
          Cf[(size_t)(r0 + j) * ldc + cidx] = v;
      }
    }
  }
}

// --------------------------- V transpose -----------------------------------
// Vt[b][d][s] = vbuf[(b*2048+s)*1024 + d]
__global__ void transpose_v(const unsigned short* __restrict__ vbuf,
                            unsigned short* __restrict__ vt) {
  __shared__ unsigned short tile[32][33];
  const int b = blockIdx.z;
  const int d0 = blockIdx.x * 32;
  const int s0 = blockIdx.y * 32;
  const int tx = threadIdx.x, ty = threadIdx.y;
#pragma unroll
  for (int i = 0; i < 32; i += 8)
    tile[ty + i][tx] =
        vbuf[(size_t)(b * 2048 + s0 + ty + i) * 1024 + d0 + tx];
  __syncthreads();
#pragma unroll
  for (int i = 0; i < 32; i += 8)
    vt[((size_t)b * 1024 + d0 + ty + i) * 2048 + s0 + tx] = tile[tx][ty + i];
}

// --------------------------- row softmax (in place, bf16) ------------------
__global__ __launch_bounds__(256) void softmax_rows(unsigned short* __restrict__ s) {
  __shared__ float red[8];
  const size_t row = blockIdx.x;
  unsigned short* p = s + row * 2048;
  const int tid = threadIdx.x;

  ushort4 u0 = *reinterpret_cast<const ushort4*>(p + tid * 8);
  ushort4 u1 = *reinterpret_cast<const ushort4*>(p + tid * 8 + 4);
  float v[8];
  v[0] = bf2f(u0.x); v[1] = bf2f(u0.y); v[2] = bf2f(u0.z); v[3] = bf2f(u0.w);
  v[4] = bf2f(u1.x); v[5] = bf2f(u1.y); v[6] = bf2f(u1.z); v[7] = bf2f(u1.w);

  float mx = v[0];
#pragma unroll
  for (int j = 1; j < 8; ++j) mx = fmaxf(mx, v[j]);
#pragma unroll
  for (int off = 32; off; off >>= 1) mx = fmaxf(mx, __shfl_xor(mx, off));
  if ((tid & 63) == 0) red[tid >> 6] = mx;
  __syncthreads();
  mx = fmaxf(fmaxf(red[0], red[1]), fmaxf(red[2], red[3]));

  float e[8], sum = 0.0f;
#pragma unroll
  for (int j = 0; j < 8; ++j) { e[j] = __expf(v[j] - mx); sum += e[j]; }
#pragma unroll
  for (int off = 32; off; off >>= 1) sum += __shfl_xor(sum, off);
  if ((tid & 63) == 0) red[4 + (tid >> 6)] = sum;
  __syncthreads();
  sum = red[4] + red[5] + red[6] + red[7];
  const float inv = 1.0f / sum;

  ushort4 o0, o1;
  o0.x = f2bf(e[0] * inv); o0.y = f2bf(e[1] * inv);
  o0.z = f2bf(e[2] * inv); o0.w = f2bf(e[3] * inv);
  o1.x = f2bf(e[4] * inv); o1.y = f2bf(e[5] * inv);
  o1.z = f2bf(e[6] * inv); o1.w = f2bf(e[7] * inv);
  *reinterpret_cast<ushort4*>(p + tid * 8) = o0;
  *reinterpret_cast<ushort4*>(p + tid * 8 + 4) = o1;
}

// ---------------------------------------------------------------------------
extern "C" void kernel_launch(void* const* d_in, const int* in_sizes, int n_in,
                              void* d_out, int out_size, void* d_ws, size_t ws_size,
                              hipStream_t stream) {
  const float* x     = (const float*)d_in[0];
  const float* Wqkv  = (const float*)d_in[1];
  const float* bqkv  = (const float*)d_in[2];
  const float* Wproj = (const float*)d_in[3];
  const float* bproj = (const float*)d_in[4];
  float* out = (float*)d_out;

  char* ws = (char*)d_ws;
  unsigned short* qk   = (unsigned short*)(ws + 0);          // 8192x2048 bf16 (33.6MB)
  unsigned short* vbuf = (unsigned short*)(ws + 33554432);   // 8192x1024 bf16 (16.8MB)
  unsigned short* xatt = (unsigned short*)(ws + 50331648);   // 8192x1024 bf16 (x_bf16 / attn_out)
  unsigned short* wq   = (unsigned short*)(ws + 67108864);   // 3072x1024 bf16
  unsigned short* wp   = (unsigned short*)(ws + 73400320);   // 1024x1024 bf16
  unsigned short* vt   = (unsigned short*)(ws + 75497472);   // 4x1024x2048 bf16
  unsigned short* sc   = (unsigned short*)(ws + 92274688);   // 4x2048x2048 bf16

  dim3 blk256(256), blk512(512);

  // 1. casts
  cvt_f32_bf16<<<2048, blk256, 0, stream>>>(x, xatt, 8192 * 1024);
  cvt_f32_bf16<<<1024, blk256, 0, stream>>>(Wqkv, wq, 3072 * 1024);
  cvt_f32_bf16<<<512, blk256, 0, stream>>>(Wproj, wp, 1024 * 1024);

  // 2a. QK projection: [8192,2048] = x @ Wqkv[0:2048]^T + b  (grid 8x32 = 256)
  gemm256<true, true><<<dim3(8, 32, 1), blk512, 0, stream>>>(
      xatt, wq, qk, bqkv, 8192, 2048, 1024, 1024, 1024, 2048, 0, 0, 0, 1.0f);

  // 2b. V projection: [8192,1024] = x @ Wqkv[2048:3072]^T + b  (grid 4x64 = 256)
  gemm_bm128<true, true><<<dim3(4, 64, 1), blk512, 0, stream>>>(
      xatt, wq + 2048 * 1024, vbuf, bqkv + 2048, 8192, 1024, 1024, 1024, 1024,
      1024, 0, 0, 0, 1.0f);

  // 3. V transpose -> Vt[b][d][s]
  transpose_v<<<dim3(32, 64, 4), dim3(32, 8), 0, stream>>>(vbuf, vt);

  // 4. scores = Q @ K^T / 32  (grid 8x8x4 = 256/slice)
  gemm256<true, false><<<dim3(8, 8, 4), blk512, 0, stream>>>(
      qk, qk + 1024, sc, nullptr, 2048, 2048, 1024, 2048, 2048, 2048,
      2048LL * 2048, 2048LL * 2048, 2048LL * 2048, 0.03125f);

  // 5. softmax rows in place
  softmax_rows<<<8192, blk256, 0, stream>>>(sc);

  // 6. attn_out = P @ Vt  (grid 4x16x4 = 256)
  gemm_bm128<true, false><<<dim3(4, 16, 4), blk512, 0, stream>>>(
      sc, vt, xatt, nullptr, 2048, 1024, 2048, 2048, 2048, 1024,
      2048LL * 2048, 1024LL * 2048, 2048LL * 1024, 1.0f);

  // 7. out = attn_out @ Wproj^T + b_proj  (grid 4x64 = 256)
  gemm_bm128<false, true><<<dim3(4, 64, 1), blk512, 0, stream>>>(
      xatt, wp, out, bproj, 8192, 1024, 1024, 1024, 1024, 1024, 0, 0, 0, 1.0f);
}